// Round 8
// baseline (404.936 us; speedup 1.0000x reference)
//
#include <hip/hip_runtime.h>
#include <math.h>

#define Bn 64
#define Dn 3072
#define Kn 512
#define En 64

static constexpr float BETA = 5.0f;

// ---- workspace layout (float offsets), ~22.9 MB ----
static constexpr size_t ZF_OFF    = 0;          // z bf16 frags (1048576)
static constexpr size_t ACCP_OFF  = 1048576;    // acc partials fp32 [(2k+h)][b][e] (4194304)
static constexpr size_t PART_OFF  = 1048576;    // kB partials [16][B][D] (3145728) - reuses ACCP
static constexpr size_t STATP_OFF = 5242880;    // stats partials [(2k+h)][3][64] (196608)
static constexpr size_t S_OFF     = 5439488;    // s fp32 [K][E] (32768)
static constexpr size_t PACC_OFF  = 5472256;    // pacc fp32 [K][E] (32768)
static constexpr size_t DOTP_OFF  = 5505024;    // dot partials [2][B][K] (65536)
static constexpr size_t NPROJ_OFF = 5570560;    // [K] (512)
static constexpr size_t XP2B_OFF  = 5571072;    // xp2 bf16 [B][K] (16384 floats)
static constexpr size_t WRECT_OFF = 5587456;    // [K][E] (32768)
static constexpr size_t FRAG_OFF  = 5620224;    // img bf16 A-frags (98304)

typedef float  f4  __attribute__((ext_vector_type(4)));
typedef __bf16 bf8 __attribute__((ext_vector_type(8)));
typedef int    i4  __attribute__((ext_vector_type(4)));

union AB { i4 i; bf8 b; };

__device__ __forceinline__ unsigned short bf16b(float x) {
  __bf16 h = (__bf16)x;
  union Cv { __bf16 h; unsigned short u; } c;
  c.h = h;
  return c.u;
}

__device__ __forceinline__ float waveAllMax(float v) {
#pragma unroll
  for (int o = 32; o; o >>= 1) v = fmaxf(v, __shfl_xor(v, o));
  return v;
}
__device__ __forceinline__ float waveAllSum(float v) {
#pragma unroll
  for (int o = 32; o; o >>= 1) v += __shfl_xor(v, o);
  return v;
}

// ---- kPT: blocks 0..95 img->bf16 A-frags; blocks 96..223 transpose w_rec ----
__global__ __launch_bounds__(256) void kPT(const float* __restrict__ img,
                                           const float* __restrict__ wrec,
                                           float* __restrict__ ws) {
  const int t = threadIdx.x;
  if (blockIdx.x < 96) {
    const int ds = blockIdx.x;
    const int T = t >> 6, l = t & 63;
    const int b = 16 * T + (l & 15);
    const int d0 = 32 * ds + 8 * (l >> 4);
    const float* p = img + (size_t)b * Dn + d0;
    unsigned short u[8];
#pragma unroll
    for (int j = 0; j < 8; ++j) u[j] = bf16b(p[j]);
    i4 v;
    v.x = (int)u[0] | ((int)u[1] << 16);
    v.y = (int)u[2] | ((int)u[3] << 16);
    v.z = (int)u[4] | ((int)u[5] << 16);
    v.w = (int)u[6] | ((int)u[7] << 16);
    ((i4*)(ws + FRAG_OFF))[(ds * 4 + T) * 64 + l] = v;
  } else {
    int g = (blockIdx.x - 96) * 256 + t;
    int k = g >> 6, e = g & 63;
    ws[WRECT_OFF + g] = wrec[(size_t)e * Kn + k];
  }
}

// ---- kA: split-d {img GEMM + dot GEMM + stats}, depth-2 w2 prefetch ----
// grid (512 k, 2 half)
__global__ __launch_bounds__(256, 4) void kA(const float* __restrict__ wproj,
                                             const float* __restrict__ w2,
                                             float* __restrict__ ws) {
  const int k = blockIdx.x, h = blockIdx.y, t = threadIdx.x;
  const int w = t >> 6, l = t & 63, elane = l & 15, dgrp = l >> 4;
  const int ecol = 16 * w + elane;
  const int n0 = h * 48;
  __shared__ float wp[Dn / 2];
  __shared__ __bf16 wpb[Dn / 2];
  const float* wpk = wproj + (size_t)k * Dn + (size_t)h * (Dn / 2);
  if (t < 192) {
    f4 x = ((const f4*)wpk)[2 * t];
    f4 y = ((const f4*)wpk)[2 * t + 1];
    ((f4*)wp)[2 * t] = x;
    ((f4*)wp)[2 * t + 1] = y;
    i4 v;
    v.x = (int)bf16b(x.x) | ((int)bf16b(x.y) << 16);
    v.y = (int)bf16b(x.z) | ((int)bf16b(x.w) << 16);
    v.z = (int)bf16b(y.x) | ((int)bf16b(y.y) << 16);
    v.w = (int)bf16b(y.z) | ((int)bf16b(y.w) << 16);
    ((i4*)wpb)[t] = v;
  }
  __syncthreads();

  const i4* afr = (const i4*)(ws + FRAG_OFF);
  const float* w2k = w2 + (size_t)k * (Dn * En);
  f4 acc0 = {0.f,0.f,0.f,0.f}, acc1 = {0.f,0.f,0.f,0.f};
  f4 acc2 = {0.f,0.f,0.f,0.f}, acc3 = {0.f,0.f,0.f,0.f};
  f4 dac0 = {0.f,0.f,0.f,0.f}, dac1 = {0.f,0.f,0.f,0.f};
  f4 dac2 = {0.f,0.f,0.f,0.f}, dac3 = {0.f,0.f,0.f,0.f};
  float ssum = 0.f, ssq = 0.f, pacc = 0.f;
  float bw0[8], bw1[8], bw2[8];
  i4 av0[4], av1[4];

#define KA_LOADB(BW, NL) {                                                       \
    _Pragma("unroll")                                                            \
    for (int j = 0; j < 8; ++j)                                                  \
      BW[j] = w2k[(size_t)((n0 + (NL)) * 32 + 8 * dgrp + j) * 64 + ecol];        \
  }
#define KA_LOADA(AV, NL) {                                                       \
    _Pragma("unroll")                                                            \
    for (int T = 0; T < 4; ++T)                                                  \
      AV[T] = afr[((size_t)(n0 + (NL)) * 4 + T) * 64 + l];                       \
  }

  KA_LOADB(bw0, 0)
  KA_LOADB(bw1, 1)
  KA_LOADA(av0, 0)

#define KA_STEP(BWC, AVC, BWP, AVP, NL) {                                        \
    if ((NL) + 2 < 48) KA_LOADB(BWP, (NL) + 2)                                   \
    if ((NL) + 1 < 48) KA_LOADA(AVP, (NL) + 1)                                   \
    bf8 bfr;                                                                     \
    _Pragma("unroll")                                                            \
    for (int j = 0; j < 8; ++j) {                                                \
      float v = BWC[j];                                                          \
      ssum += v; ssq = fmaf(v, v, ssq);                                          \
      pacc = fmaf(wp[(NL) * 32 + 8 * dgrp + j], v, pacc);                        \
      bfr[j] = (__bf16)v;                                                        \
    }                                                                            \
    bf8 wfr = *(const bf8*)&wpb[(NL) * 32 + 8 * dgrp];                           \
    AB a0, a1, a2, a3;                                                           \
    a0.i = AVC[0]; a1.i = AVC[1]; a2.i = AVC[2]; a3.i = AVC[3];                  \
    acc0 = __builtin_amdgcn_mfma_f32_16x16x32_bf16(a0.b, bfr, acc0, 0, 0, 0);    \
    acc1 = __builtin_amdgcn_mfma_f32_16x16x32_bf16(a1.b, bfr, acc1, 0, 0, 0);    \
    acc2 = __builtin_amdgcn_mfma_f32_16x16x32_bf16(a2.b, bfr, acc2, 0, 0, 0);    \
    acc3 = __builtin_amdgcn_mfma_f32_16x16x32_bf16(a3.b, bfr, acc3, 0, 0, 0);    \
    dac0 = __builtin_amdgcn_mfma_f32_16x16x32_bf16(a0.b, wfr, dac0, 0, 0, 0);    \
    dac1 = __builtin_amdgcn_mfma_f32_16x16x32_bf16(a1.b, wfr, dac1, 0, 0, 0);    \
    dac2 = __builtin_amdgcn_mfma_f32_16x16x32_bf16(a2.b, wfr, dac2, 0, 0, 0);    \
    dac3 = __builtin_amdgcn_mfma_f32_16x16x32_bf16(a3.b, wfr, dac3, 0, 0, 0);    \
  }

  for (int g = 0; g < 8; ++g) {
    const int s = 6 * g;
    KA_STEP(bw0, av0, bw2, av1, s + 0)
    KA_STEP(bw1, av1, bw0, av0, s + 1)
    KA_STEP(bw2, av0, bw1, av1, s + 2)
    KA_STEP(bw0, av1, bw2, av0, s + 3)
    KA_STEP(bw1, av0, bw0, av1, s + 4)
    KA_STEP(bw2, av1, bw1, av0, s + 5)
  }
#undef KA_STEP
#undef KA_LOADB
#undef KA_LOADA

  ssum += __shfl_xor(ssum, 16); ssum += __shfl_xor(ssum, 32);
  ssq  += __shfl_xor(ssq, 16);  ssq  += __shfl_xor(ssq, 32);
  pacc += __shfl_xor(pacc, 16); pacc += __shfl_xor(pacc, 32);
  const size_t kh = (size_t)(k * 2 + h);
  if (dgrp == 0) {
    ws[STATP_OFF + kh * 192 + 0 * 64 + ecol] = ssum;
    ws[STATP_OFF + kh * 192 + 1 * 64 + ecol] = ssq;
    ws[STATP_OFF + kh * 192 + 2 * 64 + ecol] = pacc;
  }
  if (w == 0 && elane == 0) {
#pragma unroll
    for (int T = 0; T < 4; ++T) {
      f4 d = (T == 0) ? dac0 : (T == 1) ? dac1 : (T == 2) ? dac2 : dac3;
#pragma unroll
      for (int r = 0; r < 4; ++r) {
        int b = 16 * T + 4 * dgrp + r;
        ws[DOTP_OFF + (size_t)h * (Bn * Kn) + (size_t)b * Kn + k] = d[r];
      }
    }
  }
#pragma unroll
  for (int T = 0; T < 4; ++T) {
    f4 a = (T == 0) ? acc0 : (T == 1) ? acc1 : (T == 2) ? acc2 : acc3;
#pragma unroll
    for (int r = 0; r < 4; ++r) {
      int b = 16 * T + 4 * dgrp + r;
      ws[ACCP_OFF + kh * 4096 + (size_t)b * 64 + ecol] = a[r];
    }
  }
}

// ---- kStat: fold stat partials -> S, PACC; nproj from wproj ----  grid 512, 64 thr
__global__ __launch_bounds__(64) void kStat(const float* __restrict__ wproj,
                                            float* __restrict__ ws) {
  const int k = blockIdx.x, e = threadIdx.x;
  const size_t o0 = STATP_OFF + (size_t)(2 * k) * 192;
  const size_t o1 = STATP_OFF + (size_t)(2 * k + 1) * 192;
  float ssum = ws[o0 + e] + ws[o1 + e];
  float ssq  = ws[o0 + 64 + e] + ws[o1 + 64 + e];
  float pacc = ws[o0 + 128 + e] + ws[o1 + 128 + e];
  float var = (ssq - ssum * ssum * (1.0f / Dn)) * (1.0f / (Dn - 1));
  float sv = 1.0f / (0.01f + sqrtf(fmaxf(var, 0.f)));
  ws[S_OFF + (size_t)k * 64 + e] = sv;
  ws[PACC_OFF + (size_t)k * 64 + e] = pacc;
  float np = 0.f;
  const float* wr = wproj + (size_t)k * Dn;
#pragma unroll 8
  for (int i = 0; i < 48; ++i) {
    float v = wr[i * 64 + e];
    np = fmaf(v, v, np);
  }
  np = waveAllSum(np);
  if (e == 0) ws[NPROJ_OFF + k] = np;
}

// ---- kMid: nimg, xh, softmax->xp, lat1, lat2, xh2, softmax->xp2, z-frags ----
// grid 64 (b)
__global__ __launch_bounds__(256) void kMid(const float* __restrict__ img,
                                            float* __restrict__ ws) {
  const int b = blockIdx.x;
  const int t = threadIdx.x;
  const int wid = t >> 6, lane = t & 63;
  __shared__ float xp_sh[512];
  __shared__ float red[16];
  __shared__ __align__(16) float scratch[1024];
  __shared__ __align__(16) float l1_sh[64];
  __shared__ float l2_sh[64];

  float acc = 0.f;
  const f4* irow = (const f4*)(img + (size_t)b * Dn);
#pragma unroll
  for (int i = 0; i < 3; ++i) {
    f4 v = irow[t + 256 * i];
    acc = fmaf(v.x, v.x, acc); acc = fmaf(v.y, v.y, acc);
    acc = fmaf(v.z, v.z, acc); acc = fmaf(v.w, v.w, acc);
  }
  acc = waveAllSum(acc);
  if (lane == 0) red[wid] = acc;
  __syncthreads();
  const float nimg = red[0] + red[1] + red[2] + red[3];

  float d1 = ws[DOTP_OFF + (size_t)b * Kn + t]
           + ws[DOTP_OFF + (size_t)(Bn * Kn) + (size_t)b * Kn + t];
  float d2 = ws[DOTP_OFF + (size_t)b * Kn + t + 256]
           + ws[DOTP_OFF + (size_t)(Bn * Kn) + (size_t)b * Kn + t + 256];
  float np1 = ws[NPROJ_OFF + t];
  float np2 = ws[NPROJ_OFF + t + 256];
  const float c = -(BETA / Dn);
  float x1 = c * (nimg - 2.f * d1 + np1);
  float x2 = c * (nimg - 2.f * d2 + np2);

  float m = waveAllMax(fmaxf(x1, x2));
  if (lane == 0) red[4 + wid] = m;
  __syncthreads();
  m = fmaxf(fmaxf(red[4], red[5]), fmaxf(red[6], red[7]));
  float e1 = expf(x1 - m), e2 = expf(x2 - m);
  float sv = waveAllSum(e1 + e2);
  if (lane == 0) red[8 + wid] = sv;
  __syncthreads();
  float inv = 1.f / (red[8] + red[9] + red[10] + red[11]);
  xp_sh[t] = e1 * inv;
  xp_sh[t + 256] = e2 * inv;
  __syncthreads();

  // lat1: thread = (e-quad, k-chunk); 32 iters
  const int eq = t & 15, kq = t >> 4;
  const int k0 = kq * 32;
  const f4* wrect4 = (const f4*)(ws + WRECT_OFF);
  f4 l1v = {0.f, 0.f, 0.f, 0.f};
#pragma unroll 4
  for (int i = 0; i < 32; ++i) {
    int k = k0 + i;
    l1v += xp_sh[k] * wrect4[k * 16 + eq];
  }
  ((f4*)scratch)[kq * 16 + eq] = l1v;
  __syncthreads();
  if (t < 64) {
    float s = 0.f;
#pragma unroll
    for (int q = 0; q < 16; ++q) s += scratch[q * 64 + t];
    l1_sh[t] = s;
  }
  __syncthreads();

  // lat2: 32 iters, f4 over e
  const f4* accp4 = (const f4*)(ws + ACCP_OFF);
  const f4* s4 = (const f4*)(ws + S_OFF);
  const f4* pc4 = (const f4*)(ws + PACC_OFF);
  f4 l2v = {0.f, 0.f, 0.f, 0.f};
#pragma unroll 4
  for (int i = 0; i < 32; ++i) {
    int k = k0 + i;
    f4 a0 = accp4[(size_t)(2 * k) * 1024 + b * 16 + eq];
    f4 a1 = accp4[(size_t)(2 * k + 1) * 1024 + b * 16 + eq];
    f4 svv = s4[k * 16 + eq];
    f4 pcc = pc4[k * 16 + eq];
    l2v += (xp_sh[k] * svv) * ((a0 + a1) - pcc);
  }
  __syncthreads();
  ((f4*)scratch)[kq * 16 + eq] = l2v;
  __syncthreads();
  if (t < 64) {
    float s = 0.f;
#pragma unroll
    for (int q = 0; q < 16; ++q) s += scratch[q * 64 + t];
    l2_sh[t] = s;
  }

  // xh2 for k = t, t+256 (needs l1_sh)
  float h1 = 0.f, h2 = 0.f;
#pragma unroll
  for (int i = 0; i < 16; ++i) {
    f4 lv = *(const f4*)&l1_sh[i * 4];
    f4 w1 = *(const f4*)&ws[WRECT_OFF + (size_t)t * En + i * 4];
    f4 w2v = *(const f4*)&ws[WRECT_OFF + ((size_t)t + 256) * En + i * 4];
    float a0 = lv.x - w1.x, a1 = lv.y - w1.y, a2 = lv.z - w1.z, a3 = lv.w - w1.w;
    h1 = fmaf(a0, a0, h1); h1 = fmaf(a1, a1, h1);
    h1 = fmaf(a2, a2, h1); h1 = fmaf(a3, a3, h1);
    float b0 = lv.x - w2v.x, b1 = lv.y - w2v.y, b2 = lv.z - w2v.z, b3 = lv.w - w2v.w;
    h2 = fmaf(b0, b0, h2); h2 = fmaf(b1, b1, h2);
    h2 = fmaf(b2, b2, h2); h2 = fmaf(b3, b3, h2);
  }
  const float c2 = -(BETA / En);
  x1 = c2 * h1; x2 = c2 * h2;

  m = waveAllMax(fmaxf(x1, x2));
  if (lane == 0) red[4 + wid] = m;
  __syncthreads();
  m = fmaxf(fmaxf(red[4], red[5]), fmaxf(red[6], red[7]));
  e1 = expf(x1 - m); e2 = expf(x2 - m);
  sv = waveAllSum(e1 + e2);
  if (lane == 0) red[8 + wid] = sv;
  __syncthreads();
  inv = 1.f / (red[8] + red[9] + red[10] + red[11]);
  float p1 = e1 * inv, p2 = e2 * inv;
  unsigned short* xpb = (unsigned short*)(ws + XP2B_OFF);
  xpb[(size_t)b * Kn + t] = bf16b(p1);
  xpb[(size_t)b * Kn + t + 256] = bf16b(p2);

  // z-frags for this b: z[b,k,e] = xp2*lat2[e]*s[k,e], frag layout [S][T][l][slot]
  const int T = b >> 4, bl = b & 15;
  i4* zf = (i4*)(ws + ZF_OFF);
#pragma unroll
  for (int kk = 0; kk < 2; ++kk) {
    const int k = t + 256 * kk;
    const float p = kk ? p2 : p1;
#pragma unroll
    for (int g = 0; g < 8; ++g) {
      const int dgrp = g & 3;
      const int S = 2 * k + (g >> 2);
      const int l = dgrp * 16 + bl;
      unsigned short u[8];
#pragma unroll
      for (int j = 0; j < 8; ++j) {
        int e = 8 * g + j;
        u[j] = bf16b(p * l2_sh[e] * ws[S_OFF + (size_t)k * En + e]);
      }
      i4 v;
      v.x = (int)u[0] | ((int)u[1] << 16);
      v.y = (int)u[2] | ((int)u[3] << 16);
      v.z = (int)u[4] | ((int)u[5] << 16);
      v.w = (int)u[6] | ((int)u[7] << 16);
      zf[((size_t)S * 4 + T) * 64 + l] = v;
    }
  }
}

// ---- kB: PART[ks][b][d] = sum_{k in slice} xp2*wproj + sum z*w2, depth-2 prefetch ----
// grid (48 d-tiles, 16 k-slices)
__global__ __launch_bounds__(256, 3) void kB(const float* __restrict__ wproj,
                                             const float* __restrict__ w2,
                                             float* __restrict__ ws) {
  const int dtile = blockIdx.x, ks = blockIdx.y, t = threadIdx.x;
  const int w = t >> 6, l = t & 63, elane = l & 15, dgrp = l >> 4;
  const int d = dtile * 64 + 16 * w + elane;
  const i4* zfr = (const i4*)(ws + ZF_OFF);
  f4 acc0 = {0.f,0.f,0.f,0.f}, acc1 = {0.f,0.f,0.f,0.f};
  f4 acc2 = {0.f,0.f,0.f,0.f}, acc3 = {0.f,0.f,0.f,0.f};
  f4 b0[2], b1[2], b2[2], b3[2];
  i4 a0s[4], a1s[4], a2s[4], a3s[4];

#define KB_LOADB(BW, NL) {                                                       \
    const int kk = ks * 32 + ((NL) >> 1);                                        \
    const int e0 = ((NL) & 1) * 32;                                              \
    const f4* p = (const f4*)(w2 + ((size_t)kk * Dn + d) * En + e0 + 8 * dgrp);  \
    BW[0] = p[0]; BW[1] = p[1];                                                  \
  }
#define KB_LOADA(AV, NL) {                                                       \
    _Pragma("unroll")                                                            \
    for (int T = 0; T < 4; ++T)                                                  \
      AV[T] = zfr[((size_t)(ks * 64 + (NL)) * 4 + T) * 64 + l];                  \
  }

  KB_LOADB(b0, 0)
  KB_LOADB(b1, 1)
  KB_LOADA(a0s, 0)
  KB_LOADA(a1s, 1)

#define KB_STEP(BWC, AVC, BWP, AVP, NL) {                                        \
    if ((NL) + 2 < 64) {                                                         \
      KB_LOADB(BWP, (NL) + 2)                                                    \
      KB_LOADA(AVP, (NL) + 2)                                                    \
    }                                                                            \
    bf8 bfr;                                                                     \
    _Pragma("unroll")                                                            \
    for (int j = 0; j < 4; ++j) {                                                \
      bfr[j] = (__bf16)BWC[0][j];                                                \
      bfr[4 + j] = (__bf16)BWC[1][j];                                            \
    }                                                                            \
    AB q0, q1, q2, q3;                                                           \
    q0.i = AVC[0]; q1.i = AVC[1]; q2.i = AVC[2]; q3.i = AVC[3];                  \
    acc0 = __builtin_amdgcn_mfma_f32_16x16x32_bf16(q0.b, bfr, acc0, 0, 0, 0);    \
    acc1 = __builtin_amdgcn_mfma_f32_16x16x32_bf16(q1.b, bfr, acc1, 0, 0, 0);    \
    acc2 = __builtin_amdgcn_mfma_f32_16x16x32_bf16(q2.b, bfr, acc2, 0, 0, 0);    \
    acc3 = __builtin_amdgcn_mfma_f32_16x16x32_bf16(q3.b, bfr, acc3, 0, 0, 0);    \
  }

  for (int g = 0; g < 16; ++g) {
    const int s = 4 * g;
    KB_STEP(b0, a0s, b2, a2s, s + 0)
    KB_STEP(b1, a1s, b3, a3s, s + 1)
    KB_STEP(b2, a2s, b0, a0s, s + 2)
    KB_STEP(b3, a3s, b1, a1s, s + 3)
  }
#undef KB_STEP
#undef KB_LOADB
#undef KB_LOADA

  // xp2 @ wproj term for this k-slice
  {
    const int kk0 = ks * 32;
    bf8 bw;
#pragma unroll
    for (int j = 0; j < 8; ++j)
      bw[j] = (__bf16)wproj[(size_t)(kk0 + 8 * dgrp + j) * Dn + d];
    const unsigned short* xpb = (const unsigned short*)(ws + XP2B_OFF);
    AB q0, q1, q2, q3;
    q0.i = *(const i4*)&xpb[(size_t)(0 * 16 + elane) * Kn + kk0 + 8 * dgrp];
    q1.i = *(const i4*)&xpb[(size_t)(1 * 16 + elane) * Kn + kk0 + 8 * dgrp];
    q2.i = *(const i4*)&xpb[(size_t)(2 * 16 + elane) * Kn + kk0 + 8 * dgrp];
    q3.i = *(const i4*)&xpb[(size_t)(3 * 16 + elane) * Kn + kk0 + 8 * dgrp];
    acc0 = __builtin_amdgcn_mfma_f32_16x16x32_bf16(q0.b, bw, acc0, 0, 0, 0);
    acc1 = __builtin_amdgcn_mfma_f32_16x16x32_bf16(q1.b, bw, acc1, 0, 0, 0);
    acc2 = __builtin_amdgcn_mfma_f32_16x16x32_bf16(q2.b, bw, acc2, 0, 0, 0);
    acc3 = __builtin_amdgcn_mfma_f32_16x16x32_bf16(q3.b, bw, acc3, 0, 0, 0);
  }

#pragma unroll
  for (int T = 0; T < 4; ++T) {
    f4 a = (T == 0) ? acc0 : (T == 1) ? acc1 : (T == 2) ? acc2 : acc3;
#pragma unroll
    for (int r = 0; r < 4; ++r) {
      int b = 16 * T + 4 * dgrp + r;
      ws[PART_OFF + ((size_t)ks * Bn + b) * Dn + d] = a[r];
    }
  }
}

// ---- kLoss: reduce 16 partials + loss ----  grid 64 (b)
__global__ __launch_bounds__(256) void kLoss(const float* __restrict__ img,
                                             const float* __restrict__ ws,
                                             float* __restrict__ out) {
  const int b = blockIdx.x, t = threadIdx.x;
  __shared__ float red[4];
  float acc = 0.f;
  const f4* p4 = (const f4*)(ws + PART_OFF);
  const f4* i4p = (const f4*)(img + (size_t)b * Dn);
  const int rowq = Dn / 4;
#pragma unroll
  for (int i = 0; i < 3; ++i) {
    int idx = t + 256 * i;
    f4 r = {0.f, 0.f, 0.f, 0.f};
#pragma unroll
    for (int s = 0; s < 16; ++s)
      r += p4[((size_t)s * Bn + b) * rowq + idx];
    f4 v = i4p[idx];
    float dx = r.x - v.x, dy = r.y - v.y, dz = r.z - v.z, dw = r.w - v.w;
    acc = fmaf(dx, dx, acc); acc = fmaf(dy, dy, acc);
    acc = fmaf(dz, dz, acc); acc = fmaf(dw, dw, acc);
  }
  acc = waveAllSum(acc);
  if ((t & 63) == 0) red[t >> 6] = acc;
  __syncthreads();
  if (t == 0) out[b] = (red[0] + red[1] + red[2] + red[3]) * (1.0f / Dn);
}

extern "C" void kernel_launch(void* const* d_in, const int* in_sizes, int n_in,
                              void* d_out, int out_size, void* d_ws, size_t ws_size,
                              hipStream_t stream) {
  const float* img   = (const float*)d_in[0];
  const float* wproj = (const float*)d_in[1];
  const float* w2    = (const float*)d_in[2];
  const float* wrec  = (const float*)d_in[3];
  float* ws  = (float*)d_ws;
  float* out = (float*)d_out;

  hipLaunchKernelGGL(kPT,   dim3(224), dim3(256), 0, stream, img, wrec, ws);
  hipLaunchKernelGGL(kA,    dim3(512, 2), dim3(256), 0, stream, wproj, w2, ws);
  hipLaunchKernelGGL(kStat, dim3(512), dim3(64), 0, stream, wproj, ws);
  hipLaunchKernelGGL(kMid,  dim3(64),  dim3(256), 0, stream, img, ws);
  hipLaunchKernelGGL(kB,    dim3(48, 16), dim3(256), 0, stream, wproj, w2, ws);
  hipLaunchKernelGGL(kLoss, dim3(64),  dim3(256), 0, stream, img, ws, out);
}

// Round 9
// 248.119 us; speedup vs baseline: 1.6320x; 1.6320x over previous
//
#include <hip/hip_runtime.h>
#include <math.h>

#define Bn 64
#define Dn 3072
#define Kn 512
#define En 64

static constexpr float BETA = 5.0f;

// ---- workspace layout (float offsets), ~22.9 MB ----
static constexpr size_t ZF_OFF    = 0;          // z bf16 frags (1048576)
static constexpr size_t ACCP_OFF  = 1048576;    // acc partials fp32 [(2k+h)][b][e] (4194304)
static constexpr size_t PART_OFF  = 1048576;    // kB partials [16][B][D] (3145728) - reuses ACCP
static constexpr size_t STATP_OFF = 5242880;    // stats partials [(2k+h)][3][64] (196608)
static constexpr size_t S_OFF     = 5439488;    // s fp32 [K][E] (32768)
static constexpr size_t PACC_OFF  = 5472256;    // pacc fp32 [K][E] (32768)
static constexpr size_t DOTP_OFF  = 5505024;    // dot partials [2][B][K] (65536)
static constexpr size_t NPROJ_OFF = 5570560;    // [K] (512)
static constexpr size_t XP2B_OFF  = 5571072;    // xp2 bf16 [B][K] (16384 floats)
static constexpr size_t WRECT_OFF = 5587456;    // [K][E] (32768)
static constexpr size_t FRAG_OFF  = 5620224;    // img bf16 A-frags (98304)

typedef float  f4  __attribute__((ext_vector_type(4)));
typedef __bf16 bf8 __attribute__((ext_vector_type(8)));
typedef int    i4  __attribute__((ext_vector_type(4)));

union AB { i4 i; bf8 b; };

__device__ __forceinline__ unsigned short bf16b(float x) {
  __bf16 h = (__bf16)x;
  union Cv { __bf16 h; unsigned short u; } c;
  c.h = h;
  return c.u;
}

__device__ __forceinline__ float waveAllMax(float v) {
#pragma unroll
  for (int o = 32; o; o >>= 1) v = fmaxf(v, __shfl_xor(v, o));
  return v;
}
__device__ __forceinline__ float waveAllSum(float v) {
#pragma unroll
  for (int o = 32; o; o >>= 1) v += __shfl_xor(v, o);
  return v;
}

// ---- kPT: blocks 0..95 img->bf16 A-frags; blocks 96..223 transpose w_rec ----
__global__ __launch_bounds__(256) void kPT(const float* __restrict__ img,
                                           const float* __restrict__ wrec,
                                           float* __restrict__ ws) {
  const int t = threadIdx.x;
  if (blockIdx.x < 96) {
    const int ds = blockIdx.x;
    const int T = t >> 6, l = t & 63;
    const int b = 16 * T + (l & 15);
    const int d0 = 32 * ds + 8 * (l >> 4);
    const float* p = img + (size_t)b * Dn + d0;
    unsigned short u[8];
#pragma unroll
    for (int j = 0; j < 8; ++j) u[j] = bf16b(p[j]);
    i4 v;
    v.x = (int)u[0] | ((int)u[1] << 16);
    v.y = (int)u[2] | ((int)u[3] << 16);
    v.z = (int)u[4] | ((int)u[5] << 16);
    v.w = (int)u[6] | ((int)u[7] << 16);
    ((i4*)(ws + FRAG_OFF))[(ds * 4 + T) * 64 + l] = v;
  } else {
    int g = (blockIdx.x - 96) * 256 + t;
    int k = g >> 6, e = g & 63;
    ws[WRECT_OFF + g] = wrec[(size_t)e * Kn + k];
  }
}

// ---- kA: split-d {img GEMM + dot GEMM + stats} ----  grid (512 k, 2 half)
__global__ __launch_bounds__(256, 4) void kA(const float* __restrict__ wproj,
                                             const float* __restrict__ w2,
                                             float* __restrict__ ws) {
  const int k = blockIdx.x, h = blockIdx.y, t = threadIdx.x;
  const int w = t >> 6, l = t & 63, elane = l & 15, dgrp = l >> 4;
  const int ecol = 16 * w + elane;
  const int n0 = h * 48;
  __shared__ float wp[Dn / 2];
  __shared__ __bf16 wpb[Dn / 2];
  const float* wpk = wproj + (size_t)k * Dn + (size_t)h * (Dn / 2);
  if (t < 192) {
    f4 x = ((const f4*)wpk)[2 * t];
    f4 y = ((const f4*)wpk)[2 * t + 1];
    ((f4*)wp)[2 * t] = x;
    ((f4*)wp)[2 * t + 1] = y;
    i4 v;
    v.x = (int)bf16b(x.x) | ((int)bf16b(x.y) << 16);
    v.y = (int)bf16b(x.z) | ((int)bf16b(x.w) << 16);
    v.z = (int)bf16b(y.x) | ((int)bf16b(y.y) << 16);
    v.w = (int)bf16b(y.z) | ((int)bf16b(y.w) << 16);
    ((i4*)wpb)[t] = v;
  }
  __syncthreads();

  const i4* afr = (const i4*)(ws + FRAG_OFF);
  const float* w2k = w2 + (size_t)k * (Dn * En);
  f4 acc0 = {0.f,0.f,0.f,0.f}, acc1 = {0.f,0.f,0.f,0.f};
  f4 acc2 = {0.f,0.f,0.f,0.f}, acc3 = {0.f,0.f,0.f,0.f};
  f4 dac0 = {0.f,0.f,0.f,0.f}, dac1 = {0.f,0.f,0.f,0.f};
  f4 dac2 = {0.f,0.f,0.f,0.f}, dac3 = {0.f,0.f,0.f,0.f};
  float ssum = 0.f, ssq = 0.f, pacc = 0.f;
  float bwA[8], bwB[8];
#pragma unroll
  for (int j = 0; j < 8; ++j)
    bwA[j] = w2k[(size_t)(n0 * 32 + 8 * dgrp + j) * 64 + ecol];

#define KA_STEP(BWC, BWN, NL) {                                                  \
    const int nl1 = (NL) + 1;                                                    \
    if (nl1 < 48) {                                                              \
      _Pragma("unroll")                                                          \
      for (int j = 0; j < 8; ++j)                                                \
        BWN[j] = w2k[(size_t)((n0 + nl1) * 32 + 8 * dgrp + j) * 64 + ecol];      \
    }                                                                            \
    i4 av0 = afr[((size_t)(n0 + (NL)) * 4 + 0) * 64 + l];                        \
    i4 av1 = afr[((size_t)(n0 + (NL)) * 4 + 1) * 64 + l];                        \
    i4 av2 = afr[((size_t)(n0 + (NL)) * 4 + 2) * 64 + l];                        \
    i4 av3 = afr[((size_t)(n0 + (NL)) * 4 + 3) * 64 + l];                        \
    bf8 bfr;                                                                     \
    _Pragma("unroll")                                                            \
    for (int j = 0; j < 8; ++j) {                                                \
      float v = BWC[j];                                                          \
      ssum += v; ssq = fmaf(v, v, ssq);                                          \
      pacc = fmaf(wp[(NL) * 32 + 8 * dgrp + j], v, pacc);                        \
      bfr[j] = (__bf16)v;                                                        \
    }                                                                            \
    bf8 wfr = *(const bf8*)&wpb[(NL) * 32 + 8 * dgrp];                           \
    AB a0, a1, a2, a3;                                                           \
    a0.i = av0; a1.i = av1; a2.i = av2; a3.i = av3;                              \
    acc0 = __builtin_amdgcn_mfma_f32_16x16x32_bf16(a0.b, bfr, acc0, 0, 0, 0);    \
    acc1 = __builtin_amdgcn_mfma_f32_16x16x32_bf16(a1.b, bfr, acc1, 0, 0, 0);    \
    acc2 = __builtin_amdgcn_mfma_f32_16x16x32_bf16(a2.b, bfr, acc2, 0, 0, 0);    \
    acc3 = __builtin_amdgcn_mfma_f32_16x16x32_bf16(a3.b, bfr, acc3, 0, 0, 0);    \
    dac0 = __builtin_amdgcn_mfma_f32_16x16x32_bf16(a0.b, wfr, dac0, 0, 0, 0);    \
    dac1 = __builtin_amdgcn_mfma_f32_16x16x32_bf16(a1.b, wfr, dac1, 0, 0, 0);    \
    dac2 = __builtin_amdgcn_mfma_f32_16x16x32_bf16(a2.b, wfr, dac2, 0, 0, 0);    \
    dac3 = __builtin_amdgcn_mfma_f32_16x16x32_bf16(a3.b, wfr, dac3, 0, 0, 0);    \
  }

  for (int nl = 0; nl < 48; nl += 2) {
    KA_STEP(bwA, bwB, nl)
    KA_STEP(bwB, bwA, nl + 1)
  }
#undef KA_STEP

  ssum += __shfl_xor(ssum, 16); ssum += __shfl_xor(ssum, 32);
  ssq  += __shfl_xor(ssq, 16);  ssq  += __shfl_xor(ssq, 32);
  pacc += __shfl_xor(pacc, 16); pacc += __shfl_xor(pacc, 32);
  const size_t kh = (size_t)(k * 2 + h);
  if (dgrp == 0) {
    ws[STATP_OFF + kh * 192 + 0 * 64 + ecol] = ssum;
    ws[STATP_OFF + kh * 192 + 1 * 64 + ecol] = ssq;
    ws[STATP_OFF + kh * 192 + 2 * 64 + ecol] = pacc;
  }
  if (w == 0 && elane == 0) {
#pragma unroll
    for (int T = 0; T < 4; ++T) {
      f4 d = (T == 0) ? dac0 : (T == 1) ? dac1 : (T == 2) ? dac2 : dac3;
#pragma unroll
      for (int r = 0; r < 4; ++r) {
        int b = 16 * T + 4 * dgrp + r;
        ws[DOTP_OFF + (size_t)h * (Bn * Kn) + (size_t)b * Kn + k] = d[r];
      }
    }
  }
#pragma unroll
  for (int T = 0; T < 4; ++T) {
    f4 a = (T == 0) ? acc0 : (T == 1) ? acc1 : (T == 2) ? acc2 : acc3;
#pragma unroll
    for (int r = 0; r < 4; ++r) {
      int b = 16 * T + 4 * dgrp + r;
      ws[ACCP_OFF + kh * 4096 + (size_t)b * 64 + ecol] = a[r];
    }
  }
}

// ---- kStat: fold stat partials -> S, PACC; nproj from wproj ----  grid 512, 64 thr
__global__ __launch_bounds__(64) void kStat(const float* __restrict__ wproj,
                                            float* __restrict__ ws) {
  const int k = blockIdx.x, e = threadIdx.x;
  const size_t o0 = STATP_OFF + (size_t)(2 * k) * 192;
  const size_t o1 = STATP_OFF + (size_t)(2 * k + 1) * 192;
  float ssum = ws[o0 + e] + ws[o1 + e];
  float ssq  = ws[o0 + 64 + e] + ws[o1 + 64 + e];
  float pacc = ws[o0 + 128 + e] + ws[o1 + 128 + e];
  float var = (ssq - ssum * ssum * (1.0f / Dn)) * (1.0f / (Dn - 1));
  float sv = 1.0f / (0.01f + sqrtf(fmaxf(var, 0.f)));
  ws[S_OFF + (size_t)k * 64 + e] = sv;
  ws[PACC_OFF + (size_t)k * 64 + e] = pacc;
  float np = 0.f;
  const float* wr = wproj + (size_t)k * Dn;
#pragma unroll 8
  for (int i = 0; i < 48; ++i) {
    float v = wr[i * 64 + e];
    np = fmaf(v, v, np);
  }
  np = waveAllSum(np);
  if (e == 0) ws[NPROJ_OFF + k] = np;
}

// ---- kMid: nimg, xh, softmax->xp, lat1, lat2, xh2, softmax->xp2, z-frags ----
// grid 64 (b)
__global__ __launch_bounds__(256) void kMid(const float* __restrict__ img,
                                            float* __restrict__ ws) {
  const int b = blockIdx.x;
  const int t = threadIdx.x;
  const int wid = t >> 6, lane = t & 63;
  __shared__ float xp_sh[512];
  __shared__ float red[16];
  __shared__ __align__(16) float scratch[1024];
  __shared__ __align__(16) float l1_sh[64];
  __shared__ float l2_sh[64];

  float acc = 0.f;
  const f4* irow = (const f4*)(img + (size_t)b * Dn);
#pragma unroll
  for (int i = 0; i < 3; ++i) {
    f4 v = irow[t + 256 * i];
    acc = fmaf(v.x, v.x, acc); acc = fmaf(v.y, v.y, acc);
    acc = fmaf(v.z, v.z, acc); acc = fmaf(v.w, v.w, acc);
  }
  acc = waveAllSum(acc);
  if (lane == 0) red[wid] = acc;
  __syncthreads();
  const float nimg = red[0] + red[1] + red[2] + red[3];

  float d1 = ws[DOTP_OFF + (size_t)b * Kn + t]
           + ws[DOTP_OFF + (size_t)(Bn * Kn) + (size_t)b * Kn + t];
  float d2 = ws[DOTP_OFF + (size_t)b * Kn + t + 256]
           + ws[DOTP_OFF + (size_t)(Bn * Kn) + (size_t)b * Kn + t + 256];
  float np1 = ws[NPROJ_OFF + t];
  float np2 = ws[NPROJ_OFF + t + 256];
  const float c = -(BETA / Dn);
  float x1 = c * (nimg - 2.f * d1 + np1);
  float x2 = c * (nimg - 2.f * d2 + np2);

  float m = waveAllMax(fmaxf(x1, x2));
  if (lane == 0) red[4 + wid] = m;
  __syncthreads();
  m = fmaxf(fmaxf(red[4], red[5]), fmaxf(red[6], red[7]));
  float e1 = expf(x1 - m), e2 = expf(x2 - m);
  float sv = waveAllSum(e1 + e2);
  if (lane == 0) red[8 + wid] = sv;
  __syncthreads();
  float inv = 1.f / (red[8] + red[9] + red[10] + red[11]);
  xp_sh[t] = e1 * inv;
  xp_sh[t + 256] = e2 * inv;
  __syncthreads();

  // lat1: thread = (e-quad, k-chunk); 32 iters
  const int eq = t & 15, kq = t >> 4;
  const int k0 = kq * 32;
  const f4* wrect4 = (const f4*)(ws + WRECT_OFF);
  f4 l1v = {0.f, 0.f, 0.f, 0.f};
#pragma unroll 4
  for (int i = 0; i < 32; ++i) {
    int k = k0 + i;
    l1v += xp_sh[k] * wrect4[k * 16 + eq];
  }
  ((f4*)scratch)[kq * 16 + eq] = l1v;
  __syncthreads();
  if (t < 64) {
    float s = 0.f;
#pragma unroll
    for (int q = 0; q < 16; ++q) s += scratch[q * 64 + t];
    l1_sh[t] = s;
  }
  __syncthreads();

  // lat2: 32 iters, f4 over e
  const f4* accp4 = (const f4*)(ws + ACCP_OFF);
  const f4* s4 = (const f4*)(ws + S_OFF);
  const f4* pc4 = (const f4*)(ws + PACC_OFF);
  f4 l2v = {0.f, 0.f, 0.f, 0.f};
#pragma unroll 4
  for (int i = 0; i < 32; ++i) {
    int k = k0 + i;
    f4 a0 = accp4[(size_t)(2 * k) * 1024 + b * 16 + eq];
    f4 a1 = accp4[(size_t)(2 * k + 1) * 1024 + b * 16 + eq];
    f4 svv = s4[k * 16 + eq];
    f4 pcc = pc4[k * 16 + eq];
    l2v += (xp_sh[k] * svv) * ((a0 + a1) - pcc);
  }
  __syncthreads();
  ((f4*)scratch)[kq * 16 + eq] = l2v;
  __syncthreads();
  if (t < 64) {
    float s = 0.f;
#pragma unroll
    for (int q = 0; q < 16; ++q) s += scratch[q * 64 + t];
    l2_sh[t] = s;
  }

  // xh2 for k = t, t+256 (needs l1_sh)
  float h1 = 0.f, h2 = 0.f;
#pragma unroll
  for (int i = 0; i < 16; ++i) {
    f4 lv = *(const f4*)&l1_sh[i * 4];
    f4 w1 = *(const f4*)&ws[WRECT_OFF + (size_t)t * En + i * 4];
    f4 w2v = *(const f4*)&ws[WRECT_OFF + ((size_t)t + 256) * En + i * 4];
    float a0 = lv.x - w1.x, a1 = lv.y - w1.y, a2 = lv.z - w1.z, a3 = lv.w - w1.w;
    h1 = fmaf(a0, a0, h1); h1 = fmaf(a1, a1, h1);
    h1 = fmaf(a2, a2, h1); h1 = fmaf(a3, a3, h1);
    float b0 = lv.x - w2v.x, b1 = lv.y - w2v.y, b2 = lv.z - w2v.z, b3 = lv.w - w2v.w;
    h2 = fmaf(b0, b0, h2); h2 = fmaf(b1, b1, h2);
    h2 = fmaf(b2, b2, h2); h2 = fmaf(b3, b3, h2);
  }
  const float c2 = -(BETA / En);
  x1 = c2 * h1; x2 = c2 * h2;

  m = waveAllMax(fmaxf(x1, x2));
  if (lane == 0) red[4 + wid] = m;
  __syncthreads();
  m = fmaxf(fmaxf(red[4], red[5]), fmaxf(red[6], red[7]));
  e1 = expf(x1 - m); e2 = expf(x2 - m);
  sv = waveAllSum(e1 + e2);
  if (lane == 0) red[8 + wid] = sv;
  __syncthreads();
  inv = 1.f / (red[8] + red[9] + red[10] + red[11]);
  float p1 = e1 * inv, p2 = e2 * inv;
  unsigned short* xpb = (unsigned short*)(ws + XP2B_OFF);
  xpb[(size_t)b * Kn + t] = bf16b(p1);
  xpb[(size_t)b * Kn + t + 256] = bf16b(p2);

  // z-frags for this b: z[b,k,e] = xp2*lat2[e]*s[k,e], frag layout [S][T][l][slot]
  const int T = b >> 4, bl = b & 15;
  i4* zf = (i4*)(ws + ZF_OFF);
#pragma unroll
  for (int kk = 0; kk < 2; ++kk) {
    const int k = t + 256 * kk;
    const float p = kk ? p2 : p1;
#pragma unroll
    for (int g = 0; g < 8; ++g) {
      const int dgrp = g & 3;
      const int S = 2 * k + (g >> 2);
      const int l = dgrp * 16 + bl;
      unsigned short u[8];
#pragma unroll
      for (int j = 0; j < 8; ++j) {
        int e = 8 * g + j;
        u[j] = bf16b(p * l2_sh[e] * ws[S_OFF + (size_t)k * En + e]);
      }
      i4 v;
      v.x = (int)u[0] | ((int)u[1] << 16);
      v.y = (int)u[2] | ((int)u[3] << 16);
      v.z = (int)u[4] | ((int)u[5] << 16);
      v.w = (int)u[6] | ((int)u[7] << 16);
      zf[((size_t)S * 4 + T) * 64 + l] = v;
    }
  }
}

// ---- kB: PART[ks][b][d] = sum_{k in slice} xp2*wproj + sum z*w2 ----
// grid (48 d-tiles, 16 k-slices)
__global__ __launch_bounds__(256, 3) void kB(const float* __restrict__ wproj,
                                             const float* __restrict__ w2,
                                             float* __restrict__ ws) {
  const int dtile = blockIdx.x, ks = blockIdx.y, t = threadIdx.x;
  const int w = t >> 6, l = t & 63, elane = l & 15, dgrp = l >> 4;
  const int d = dtile * 64 + 16 * w + elane;
  const i4* zfr = (const i4*)(ws + ZF_OFF);
  f4 acc0 = {0.f,0.f,0.f,0.f}, acc1 = {0.f,0.f,0.f,0.f};
  f4 acc2 = {0.f,0.f,0.f,0.f}, acc3 = {0.f,0.f,0.f,0.f};
  f4 bwA[2], bwB[2];
  i4 avA[4], avB[4];
  {
    const f4* p = (const f4*)(w2 + ((size_t)(ks * 32) * Dn + d) * En + 8 * dgrp);
    bwA[0] = p[0]; bwA[1] = p[1];
#pragma unroll
    for (int T = 0; T < 4; ++T) avA[T] = zfr[((size_t)(ks * 64) * 4 + T) * 64 + l];
  }

#define KB_ITER(BWC, BWN, AVC, AVN, N) {                                         \
    const int np1 = (N) + 1;                                                     \
    if (np1 < 64) {                                                              \
      const int kk = ks * 32 + (np1 >> 1);                                       \
      const int e0 = (np1 & 1) * 32;                                             \
      const f4* p = (const f4*)(w2 + ((size_t)kk * Dn + d) * En + e0 + 8 * dgrp);\
      BWN[0] = p[0]; BWN[1] = p[1];                                              \
      _Pragma("unroll")                                                          \
      for (int T = 0; T < 4; ++T)                                                \
        AVN[T] = zfr[((size_t)(ks * 64 + np1) * 4 + T) * 64 + l];                \
    }                                                                            \
    bf8 bfr;                                                                     \
    _Pragma("unroll")                                                            \
    for (int j = 0; j < 4; ++j) {                                                \
      bfr[j] = (__bf16)BWC[0][j];                                                \
      bfr[4 + j] = (__bf16)BWC[1][j];                                            \
    }                                                                            \
    AB a0, a1, a2, a3;                                                           \
    a0.i = AVC[0]; a1.i = AVC[1]; a2.i = AVC[2]; a3.i = AVC[3];                  \
    acc0 = __builtin_amdgcn_mfma_f32_16x16x32_bf16(a0.b, bfr, acc0, 0, 0, 0);    \
    acc1 = __builtin_amdgcn_mfma_f32_16x16x32_bf16(a1.b, bfr, acc1, 0, 0, 0);    \
    acc2 = __builtin_amdgcn_mfma_f32_16x16x32_bf16(a2.b, bfr, acc2, 0, 0, 0);    \
    acc3 = __builtin_amdgcn_mfma_f32_16x16x32_bf16(a3.b, bfr, acc3, 0, 0, 0);    \
  }

  for (int n = 0; n < 64; n += 2) {
    KB_ITER(bwA, bwB, avA, avB, n)
    KB_ITER(bwB, bwA, avB, avA, n + 1)
  }
#undef KB_ITER

  // xp2 @ wproj term for this k-slice
  {
    const int kk0 = ks * 32;
    bf8 bw;
#pragma unroll
    for (int j = 0; j < 8; ++j)
      bw[j] = (__bf16)wproj[(size_t)(kk0 + 8 * dgrp + j) * Dn + d];
    const unsigned short* xpb = (const unsigned short*)(ws + XP2B_OFF);
    AB a0, a1, a2, a3;
    a0.i = *(const i4*)&xpb[(size_t)(0 * 16 + elane) * Kn + kk0 + 8 * dgrp];
    a1.i = *(const i4*)&xpb[(size_t)(1 * 16 + elane) * Kn + kk0 + 8 * dgrp];
    a2.i = *(const i4*)&xpb[(size_t)(2 * 16 + elane) * Kn + kk0 + 8 * dgrp];
    a3.i = *(const i4*)&xpb[(size_t)(3 * 16 + elane) * Kn + kk0 + 8 * dgrp];
    acc0 = __builtin_amdgcn_mfma_f32_16x16x32_bf16(a0.b, bw, acc0, 0, 0, 0);
    acc1 = __builtin_amdgcn_mfma_f32_16x16x32_bf16(a1.b, bw, acc1, 0, 0, 0);
    acc2 = __builtin_amdgcn_mfma_f32_16x16x32_bf16(a2.b, bw, acc2, 0, 0, 0);
    acc3 = __builtin_amdgcn_mfma_f32_16x16x32_bf16(a3.b, bw, acc3, 0, 0, 0);
  }

#pragma unroll
  for (int T = 0; T < 4; ++T) {
    f4 a = (T == 0) ? acc0 : (T == 1) ? acc1 : (T == 2) ? acc2 : acc3;
#pragma unroll
    for (int r = 0; r < 4; ++r) {
      int b = 16 * T + 4 * dgrp + r;
      ws[PART_OFF + ((size_t)ks * Bn + b) * Dn + d] = a[r];
    }
  }
}

// ---- kLoss: reduce 16 partials + loss ----  grid 64 (b)
__global__ __launch_bounds__(256) void kLoss(const float* __restrict__ img,
                                             const float* __restrict__ ws,
                                             float* __restrict__ out) {
  const int b = blockIdx.x, t = threadIdx.x;
  __shared__ float red[4];
  float acc = 0.f;
  const f4* p4 = (const f4*)(ws + PART_OFF);
  const f4* i4p = (const f4*)(img + (size_t)b * Dn);
  const int rowq = Dn / 4;
#pragma unroll
  for (int i = 0; i < 3; ++i) {
    int idx = t + 256 * i;
    f4 r = {0.f, 0.f, 0.f, 0.f};
#pragma unroll
    for (int s = 0; s < 16; ++s)
      r += p4[((size_t)s * Bn + b) * rowq + idx];
    f4 v = i4p[idx];
    float dx = r.x - v.x, dy = r.y - v.y, dz = r.z - v.z, dw = r.w - v.w;
    acc = fmaf(dx, dx, acc); acc = fmaf(dy, dy, acc);
    acc = fmaf(dz, dz, acc); acc = fmaf(dw, dw, acc);
  }
  acc = waveAllSum(acc);
  if ((t & 63) == 0) red[t >> 6] = acc;
  __syncthreads();
  if (t == 0) out[b] = (red[0] + red[1] + red[2] + red[3]) * (1.0f / Dn);
}

extern "C" void kernel_launch(void* const* d_in, const int* in_sizes, int n_in,
                              void* d_out, int out_size, void* d_ws, size_t ws_size,
                              hipStream_t stream) {
  const float* img   = (const float*)d_in[0];
  const float* wproj = (const float*)d_in[1];
  const float* w2    = (const float*)d_in[2];
  const float* wrec  = (const float*)d_in[3];
  float* ws  = (float*)d_ws;
  float* out = (float*)d_out;

  hipLaunchKernelGGL(kPT,   dim3(224), dim3(256), 0, stream, img, wrec, ws);
  hipLaunchKernelGGL(kA,    dim3(512, 2), dim3(256), 0, stream, wproj, w2, ws);
  hipLaunchKernelGGL(kStat, dim3(512), dim3(64), 0, stream, wproj, ws);
  hipLaunchKernelGGL(kMid,  dim3(64),  dim3(256), 0, stream, img, ws);
  hipLaunchKernelGGL(kB,    dim3(48, 16), dim3(256), 0, stream, wproj, w2, ws);
  hipLaunchKernelGGL(kLoss, dim3(64),  dim3(256), 0, stream, img, ws, out);
}